// Round 4
// baseline (204.179 us; speedup 1.0000x reference)
//
#include <hip/hip_runtime.h>
#include <hip/hip_bf16.h>
#include <stdint.h>

// Problem constants (fixed by setup_inputs)
#define PRIME 2147483647u
#define GAMMA 0.3f
#define K_HASH 128
#define S_SET 8
#define NB 4
#define LQ 1024
#define LK 1024
#define EDIM 512

typedef unsigned short ushort_t;
typedef __attribute__((ext_vector_type(8))) short short8;
typedef __attribute__((ext_vector_type(4))) float f32x4;
typedef __attribute__((ext_vector_type(2))) unsigned short u16x2;

static __device__ __forceinline__ unsigned short f2bf(float f) {
    unsigned u = __builtin_bit_cast(unsigned, f);
    u += 0x7FFFu + ((u >> 16) & 1u);   // RNE (no NaN in this problem)
    return (unsigned short)(u >> 16);
}

// async global->LDS, 16B per lane; LDS dst must be lane-contiguous.
static __device__ __forceinline__ void glds16(const void* g, void* l) {
    __builtin_amdgcn_global_load_lds(
        (const __attribute__((address_space(1))) unsigned int*)g,
        (__attribute__((address_space(3))) unsigned int*)l, 16, 0, 0);
}

#define SWZ(r) ((((r) >> 2) & 3) ^ ((r) & 3))

// packed nonmatch accumulate: acc += per-half min(a^b, 1)
// (v_xor + v_pk_min_u16 + v_add = 3 ops per 2 hash slots)
static __device__ __forceinline__ unsigned nm2(unsigned acc, unsigned a, unsigned b) {
    unsigned x = a ^ b;
    u16x2 xv = __builtin_bit_cast(u16x2, x);
    u16x2 one; one.x = 1; one.y = 1;
    u16x2 t = __builtin_elementwise_min(xv, one);
    return acc + __builtin_bit_cast(unsigned, t);   // halves <= 64: no carry
}
static __device__ __forceinline__ unsigned nm8(unsigned acc, int4 q, int4 k) {
    acc = nm2(acc, (unsigned)q.x, (unsigned)k.x);
    acc = nm2(acc, (unsigned)q.y, (unsigned)k.y);
    acc = nm2(acc, (unsigned)q.z, (unsigned)k.z);
    acc = nm2(acc, (unsigned)q.w, (unsigned)k.w);
    return acc;
}

// ---------------------------------------------------------------------------
// 0) f32 -> bf16 pre-convert for value / Wv / Wo
// ---------------------------------------------------------------------------
#define CVT_N0 (NB * LK * EDIM)
#define CVT_N1 (EDIM * EDIM)
#define CVT_N2 (EDIM * EDIM)
__global__ __launch_bounds__(256) void cvt_kernel(
        const float* __restrict__ v, const float* __restrict__ wv,
        const float* __restrict__ wo,
        ushort_t* __restrict__ vb, ushort_t* __restrict__ wvb,
        ushort_t* __restrict__ wob) {
    size_t i = ((size_t)blockIdx.x * 256 + threadIdx.x) * 8;
    const float* src; ushort_t* dst; size_t off;
    if (i < CVT_N0)                { src = v;  dst = vb;  off = i; }
    else if (i < CVT_N0 + CVT_N1)  { src = wv; dst = wvb; off = i - CVT_N0; }
    else                           { src = wo; dst = wob; off = i - CVT_N0 - CVT_N1; }
    float4 a = *(const float4*)(src + off);
    float4 b = *(const float4*)(src + off + 4);
    ushort4 o0, o1;
    o0.x = f2bf(a.x); o0.y = f2bf(a.y); o0.z = f2bf(a.z); o0.w = f2bf(a.w);
    o1.x = f2bf(b.x); o1.y = f2bf(b.y); o1.z = f2bf(b.z); o1.w = f2bf(b.w);
    *(ushort4*)(dst + off)     = o0;
    *(ushort4*)(dst + off + 4) = o1;
}

// ---------------------------------------------------------------------------
// 1) MinHash signatures -> low-16-bit truncated (equality FP rate 2^-16,
//    output-level effect ~3e-7 << 5e-4 threshold). Also zeroes rowsum buf.
// ---------------------------------------------------------------------------
__global__ __launch_bounds__(128) void sig_kernel(
        const int* __restrict__ ts_q, const int* __restrict__ ts_k,
        const int* __restrict__ ha, const int* __restrict__ hb,
        ushort_t* __restrict__ sig_q, ushort_t* __restrict__ sig_k,
        float* __restrict__ rs) {
    int blk = blockIdx.x;
    int k = threadIdx.x;
    if (blk < 32) rs[blk * 128 + k] = 0.f;   // zero rowsum[4096] (ws is poisoned)
    const int* ts = (blk < NB * LQ) ? ts_q : ts_k;
    ushort_t* sig = (blk < NB * LQ) ? sig_q : sig_k;
    int idx = blk & (NB * LQ - 1);
    unsigned long long a  = (unsigned)ha[k];
    unsigned long long bb = (unsigned)hb[k];
    __shared__ int ids[S_SET];
    if (k < S_SET) ids[k] = ts[idx * S_SET + k];
    __syncthreads();
    unsigned mn = 0xFFFFFFFFu;
    #pragma unroll
    for (int s = 0; s < S_SET; s++) {
        unsigned long long x = a * (unsigned long long)(unsigned)ids[s] + bb;
        x = (x & PRIME) + (x >> 31);      // 2^31 == 1 (mod 2^31-1)
        x = (x & PRIME) + (x >> 31);
        unsigned r = (unsigned)x;
        if (r >= PRIME) r -= PRIME;
        mn = (r < mn) ? r : mn;
    }
    sig[idx * K_HASH + k] = (ushort_t)mn;
}

// ---------------------------------------------------------------------------
// 2) Jaccard v2: 128x128 tile, 256 thr, 8x8 per thread, packed-u16 compares.
//    Fused per-row sums -> atomicAdd into rs. Swizzled LDS:
//      Qs: 16-word rows, group at (g+(r>>3))&3  -> qv reads conflict-free
//      Ks: 17-word rows, group at (g+(r>>5))&3  -> kv reads 2-way (free)
// ---------------------------------------------------------------------------
__global__ __launch_bounds__(256) void jaccard_kernel(
        const ushort_t* __restrict__ sig_q, const ushort_t* __restrict__ sig_k,
        ushort_t* __restrict__ P, float* __restrict__ rs) {
    __shared__ int Qs[128 * 16];          // 8 KB
    __shared__ int Ks[128 * 17];          // 8.5 KB
    __shared__ float lut[K_HASH + 1];
    int tid = threadIdx.x;
    if (tid <= K_HASH) {
        float r = (float)(K_HASH - tid) / (float)(K_HASH + tid); // (1-J)/(1+J)
        lut[tid] = expf(expf(-GAMMA * (2.0f * S_SET) * r));      // softmax numer
    }
    int b = blockIdx.z;
    int q0 = blockIdx.y * 128, j0 = blockIdx.x * 128;
    const int4* gq = (const int4*)(sig_q + ((size_t)b * LQ + q0) * K_HASH);
    const int4* gk = (const int4*)(sig_k + ((size_t)b * LK + j0) * K_HASH);
    int tx = tid & 15, ty = tid >> 4;
    unsigned acc[8][8] = {};
    int r0 = tid >> 2, g0 = tid & 3;      // staging item tid
    int r1 = (tid + 256) >> 2;            // staging item tid+256 (same g)
    #pragma unroll 1
    for (int ch = 0; ch < 4; ch++) {      // 4 chunks x 32 hash slots (16 words)
        __syncthreads();
        *(int4*)&Qs[r0 * 16 + ((g0 + (r0 >> 3)) & 3) * 4] = gq[r0 * 16 + ch * 4 + g0];
        *(int4*)&Qs[r1 * 16 + ((g0 + (r1 >> 3)) & 3) * 4] = gq[r1 * 16 + ch * 4 + g0];
        *(int4*)&Ks[r0 * 17 + ((g0 + (r0 >> 5)) & 3) * 4] = gk[r0 * 16 + ch * 4 + g0];
        *(int4*)&Ks[r1 * 17 + ((g0 + (r1 >> 5)) & 3) * 4] = gk[r1 * 16 + ch * 4 + g0];
        __syncthreads();
        #pragma unroll
        for (int cc = 0; cc < 4; cc++) {  // 4 words (8 slots) per pass
            int4 qv[8], kv[8];
            #pragma unroll
            for (int i = 0; i < 8; i++)
                qv[i] = *(const int4*)&Qs[(ty * 8 + i) * 16 + ((cc + ty) & 3) * 4];
            #pragma unroll
            for (int j = 0; j < 8; j++)
                kv[j] = *(const int4*)&Ks[(tx * 8 + j) * 17 + ((cc + (tx >> 2)) & 3) * 4];
            #pragma unroll
            for (int i = 0; i < 8; i++)
                #pragma unroll
                for (int j = 0; j < 8; j++)
                    acc[i][j] = nm8(acc[i][j], qv[i], kv[j]);
        }
    }
    // counts -> P (bf16) + per-row partial sums
    ushort_t* Pb = P + (size_t)b * LQ * LK;
    float fsum[8];
    #pragma unroll
    for (int i = 0; i < 8; i++) {
        float s = 0.f;
        ushort_t o[8];
        #pragma unroll
        for (int j = 0; j < 8; j++) {
            unsigned nm = (acc[i][j] & 0xFFFFu) + (acc[i][j] >> 16);
            float p = lut[K_HASH - nm];
            s += p;
            o[j] = f2bf(p);
        }
        fsum[i] = s;
        int row = q0 + ty * 8 + i;
        *(short8*)&Pb[(size_t)row * LK + j0 + tx * 8] = *(const short8*)o;
    }
    __syncthreads();                      // compute done; reuse Qs as f32 scratch
    float* fs = (float*)Qs;               // [128 rows][16 tx]
    #pragma unroll
    for (int i = 0; i < 8; i++) fs[(ty * 8 + i) * 16 + tx] = fsum[i];
    __syncthreads();
    if (tid < 128) {
        float s = 0.f;
        #pragma unroll
        for (int t = 0; t < 16; t++) s += fs[tid * 16 + t];
        atomicAdd(&rs[(size_t)b * LQ + q0 + tid], s);
    }
}

// ---------------------------------------------------------------------------
// 4) bf16 BT-GEMM: C[M,N] = A[M,K] @ B[N,K]^T (+epilogue), f32 accum.
//    128x64 tile, 256 thr, glds width-16, XOR-swizzled LDS, dbuf.
// ---------------------------------------------------------------------------
#define EPI_ROWBIAS  0
#define EPI_ROWDIV   1
#define EPI_COLBIAS  2

template<int OUTF32, int MODE>
__global__ __launch_bounds__(256) void btgemm_kernel(
        const ushort_t* __restrict__ A, const ushort_t* __restrict__ B,
        void* __restrict__ C,
        const float* __restrict__ bias, const float* __restrict__ scale,
        int lda, int ldb, int ldc, int Kd,
        long long sA, long long sB, long long sC, long long sS) {
    __shared__ ushort_t As[2][128 * 32];
    __shared__ ushort_t Bs[2][64 * 32];
    int z = blockIdx.z;
    int m0 = blockIdx.y * 128, n0 = blockIdx.x * 64;
    int tid = threadIdx.x;
    int w = tid >> 6, lane = tid & 63;
    int wm = (w & 1) * 64, wn = (w >> 1) * 32;
    int mrow = lane & 15, kg = lane >> 4;

    int r = tid >> 2, c = (tid & 3) ^ SWZ(r);
    const ushort_t* pa0 = A + (size_t)z * sA + (size_t)(m0 + r) * lda + c * 8;
    const ushort_t* pa1 = pa0 + (size_t)64 * lda;
    const ushort_t* pb  = B + (size_t)z * sB + (size_t)(n0 + r) * ldb + c * 8;

    int aoff[4], boff[2];
    #pragma unroll
    for (int i = 0; i < 4; i++) {
        int R = wm + i * 16 + mrow;
        aoff[i] = R * 32 + (kg ^ SWZ(R)) * 8;
    }
    #pragma unroll
    for (int j = 0; j < 2; j++) {
        int R = wn + j * 16 + mrow;
        boff[j] = R * 32 + (kg ^ SWZ(R)) * 8;
    }

    f32x4 acc[4][2] = {};
    int nK = Kd >> 5;
    glds16(pa0, &As[0][tid * 8]);
    glds16(pa1, &As[0][2048 + tid * 8]);
    glds16(pb,  &Bs[0][tid * 8]);
    for (int i = 0; i < nK; i++) {
        __syncthreads();
        int cur = i & 1, nxt = cur ^ 1;
        if (i + 1 < nK) {
            int k0 = (i + 1) << 5;
            glds16(pa0 + k0, &As[nxt][tid * 8]);
            glds16(pa1 + k0, &As[nxt][2048 + tid * 8]);
            glds16(pb  + k0, &Bs[nxt][tid * 8]);
        }
        short8 af[4], bh[2];
        #pragma unroll
        for (int ii = 0; ii < 4; ii++) af[ii] = *(const short8*)&As[cur][aoff[ii]];
        #pragma unroll
        for (int jj = 0; jj < 2; jj++) bh[jj] = *(const short8*)&Bs[cur][boff[jj]];
        #pragma unroll
        for (int ii = 0; ii < 4; ii++)
            #pragma unroll
            for (int jj = 0; jj < 2; jj++)
                acc[ii][jj] = __builtin_amdgcn_mfma_f32_16x16x32_bf16(
                                  af[ii], bh[jj], acc[ii][jj], 0, 0, 0);
    }

    const float* sc = scale + (size_t)z * sS;
    int col = lane & 15, rbase = (lane >> 4) * 4;
    #pragma unroll
    for (int ii = 0; ii < 4; ii++) {
        #pragma unroll
        for (int jj = 0; jj < 2; jj++) {
            #pragma unroll
            for (int rr = 0; rr < 4; rr++) {
                int gm = m0 + wm + ii * 16 + rbase + rr;
                int gn = n0 + wn + jj * 16 + col;
                float v = acc[ii][jj][rr];
                if (MODE == EPI_ROWBIAS)     v += bias[gm];
                else if (MODE == EPI_ROWDIV) v /= sc[gm];
                else                         v += bias[gn];
                size_t cix = (size_t)z * sC + (size_t)gm * ldc + gn;
                if (OUTF32) ((float*)C)[cix] = v;
                else        ((ushort_t*)C)[cix] = f2bf(v);
            }
        }
    }
}

// ---------------------------------------------------------------------------
extern "C" void kernel_launch(void* const* d_in, const int* in_sizes, int n_in,
                              void* d_out, int out_size, void* d_ws, size_t ws_size,
                              hipStream_t stream) {
    // inputs: 0 query 1 key 2 value 3 ts_q 4 ts_k 5 ha 6 hb 7 Wq 8 bq 9 Wk 10 bk
    //         11 Wv 12 bv 13 Wo 14 bo   (q/k projections are dead code)
    const float* value = (const float*)d_in[2];
    const int* tsq = (const int*)d_in[3];
    const int* tsk = (const int*)d_in[4];
    const int* ha  = (const int*)d_in[5];
    const int* hb  = (const int*)d_in[6];
    const float* Wv = (const float*)d_in[11];
    const float* bv = (const float*)d_in[12];
    const float* Wo = (const float*)d_in[13];
    const float* bo = (const float*)d_in[14];
    float* out = (float*)d_out;

    char* ws = (char*)d_ws;
    ushort_t* sigq   = (ushort_t*)(ws);                              // 1 MB
    ushort_t* sigk   = (ushort_t*)(ws + (1ull << 20));               // 1 MB
    ushort_t* P      = (ushort_t*)(ws + (4ull << 20));               // 8 MB
    float* rs        = (float*)(ws + (12ull << 20));                 // 16 KB
    ushort_t* Vt     = (ushort_t*)(ws + (12ull << 20) + (1ull << 16)); // 4 MB [512 x 4096]
    ushort_t* ctx    = (ushort_t*)(ws + (17ull << 20));              // 4 MB [4096 x 512]
    ushort_t* Vb     = (ushort_t*)(ws + (21ull << 20));              // 4 MB [4096 x 512]
    ushort_t* Wvb    = (ushort_t*)(ws + (25ull << 20));              // 512 KB
    ushort_t* Wob    = (ushort_t*)(ws + (25ull << 20) + (512ull << 10)); // 512 KB

    // 0) f32 -> bf16 for GEMM operands
    cvt_kernel<<<(CVT_N0 + CVT_N1 + CVT_N2) / (256 * 8), 256, 0, stream>>>(
        value, Wv, Wo, Vb, Wvb, Wob);

    // 1) signatures (+ zero rs)
    sig_kernel<<<2 * NB * LQ, 128, 0, stream>>>(tsq, tsk, ha, hb, sigq, sigk, rs);

    // 2) P = exp(score) (bf16) + row sums into rs
    jaccard_kernel<<<dim3(LK / 128, LQ / 128, NB), 256, 0, stream>>>(sigq, sigk, P, rs);

    // 4) Vt[d, b*1024+j] = sum_e Wvb[d,e]*Vb[b*1024+j, e] + bv[d]
    btgemm_kernel<0, EPI_ROWBIAS><<<dim3(4096 / 64, 512 / 128, 1), 256, 0, stream>>>(
        Wvb, Vb, Vt, bv, rs /*unused*/,
        EDIM, EDIM, NB * LK, EDIM, 0LL, 0LL, 0LL, 0LL);

    // 5) ctx[b*1024+q, d] = (1/rs[b,q]) * sum_j P[b,q,j]*Vt[d, b*1024+j]
    btgemm_kernel<0, EPI_ROWDIV><<<dim3(EDIM / 64, LQ / 128, NB), 256, 0, stream>>>(
        P, Vt, ctx, bv /*unused*/, rs,
        LK, NB * LK, EDIM, LK,
        (long long)LQ * LK, (long long)LK, (long long)LQ * EDIM, (long long)LQ);

    // 6) out[bq, n] = sum_e ctx[bq,e]*Wob[n,e] + bo[n]  (f32 -> d_out)
    btgemm_kernel<1, EPI_COLBIAS><<<dim3(EDIM / 64, NB * LQ / 128, 1), 256, 0, stream>>>(
        ctx, Wob, out, bo, rs /*unused*/,
        EDIM, EDIM, EDIM, EDIM, 0LL, 0LL, 0LL, 0LL);
}

// Round 5
// 185.253 us; speedup vs baseline: 1.1022x; 1.1022x over previous
//
#include <hip/hip_runtime.h>
#include <hip/hip_bf16.h>
#include <stdint.h>

// Problem constants (fixed by setup_inputs)
#define PRIME 2147483647u
#define GAMMA 0.3f
#define K_HASH 128
#define S_SET 8
#define NB 4
#define LQ 1024
#define LK 1024
#define EDIM 512

typedef unsigned short ushort_t;
typedef __attribute__((ext_vector_type(8))) short short8;
typedef __attribute__((ext_vector_type(4))) float f32x4;
typedef __attribute__((ext_vector_type(2))) unsigned short u16x2;

static __device__ __forceinline__ unsigned short f2bf(float f) {
    unsigned u = __builtin_bit_cast(unsigned, f);
    u += 0x7FFFu + ((u >> 16) & 1u);   // RNE (no NaN in this problem)
    return (unsigned short)(u >> 16);
}

// async global->LDS, 16B per lane; LDS dst must be lane-contiguous.
static __device__ __forceinline__ void glds16(const void* g, void* l) {
    __builtin_amdgcn_global_load_lds(
        (const __attribute__((address_space(1))) unsigned int*)g,
        (__attribute__((address_space(3))) unsigned int*)l, 16, 0, 0);
}

#define SWZ(r) ((((r) >> 2) & 3) ^ ((r) & 3))

// packed nonmatch accumulate: acc += per-half min(a^b, 1)
// (v_xor + v_pk_min_u16 + v_add = 3 ops per 2 hash slots)
static __device__ __forceinline__ unsigned nm2(unsigned acc, unsigned a, unsigned b) {
    unsigned x = a ^ b;
    u16x2 xv = __builtin_bit_cast(u16x2, x);
    u16x2 one; one.x = 1; one.y = 1;
    u16x2 t = __builtin_elementwise_min(xv, one);
    return acc + __builtin_bit_cast(unsigned, t);   // halves <= 64: no carry
}
static __device__ __forceinline__ unsigned nm8(unsigned acc, int4 q, int4 k) {
    acc = nm2(acc, (unsigned)q.x, (unsigned)k.x);
    acc = nm2(acc, (unsigned)q.y, (unsigned)k.y);
    acc = nm2(acc, (unsigned)q.z, (unsigned)k.z);
    acc = nm2(acc, (unsigned)q.w, (unsigned)k.w);
    return acc;
}

// ---------------------------------------------------------------------------
// 0) f32 -> bf16 pre-convert for value / Wv / Wo
// ---------------------------------------------------------------------------
#define CVT_N0 (NB * LK * EDIM)
#define CVT_N1 (EDIM * EDIM)
#define CVT_N2 (EDIM * EDIM)
__global__ __launch_bounds__(256) void cvt_kernel(
        const float* __restrict__ v, const float* __restrict__ wv,
        const float* __restrict__ wo,
        ushort_t* __restrict__ vb, ushort_t* __restrict__ wvb,
        ushort_t* __restrict__ wob) {
    size_t i = ((size_t)blockIdx.x * 256 + threadIdx.x) * 8;
    const float* src; ushort_t* dst; size_t off;
    if (i < CVT_N0)                { src = v;  dst = vb;  off = i; }
    else if (i < CVT_N0 + CVT_N1)  { src = wv; dst = wvb; off = i - CVT_N0; }
    else                           { src = wo; dst = wob; off = i - CVT_N0 - CVT_N1; }
    float4 a = *(const float4*)(src + off);
    float4 b = *(const float4*)(src + off + 4);
    ushort4 o0, o1;
    o0.x = f2bf(a.x); o0.y = f2bf(a.y); o0.z = f2bf(a.z); o0.w = f2bf(a.w);
    o1.x = f2bf(b.x); o1.y = f2bf(b.y); o1.z = f2bf(b.z); o1.w = f2bf(b.w);
    *(ushort4*)(dst + off)     = o0;
    *(ushort4*)(dst + off + 4) = o1;
}

// ---------------------------------------------------------------------------
// 1) MinHash signatures -> low-16-bit truncated (equality FP rate 2^-16,
//    output-level effect ~1e-6 << 5e-4 threshold). Also zeroes rowsum buf.
// ---------------------------------------------------------------------------
__global__ __launch_bounds__(128) void sig_kernel(
        const int* __restrict__ ts_q, const int* __restrict__ ts_k,
        const int* __restrict__ ha, const int* __restrict__ hb,
        ushort_t* __restrict__ sig_q, ushort_t* __restrict__ sig_k,
        float* __restrict__ rs) {
    int blk = blockIdx.x;
    int k = threadIdx.x;
    if (blk < 32) rs[blk * 128 + k] = 0.f;   // zero rowsum[4096] (ws is poisoned)
    const int* ts = (blk < NB * LQ) ? ts_q : ts_k;
    ushort_t* sig = (blk < NB * LQ) ? sig_q : sig_k;
    int idx = blk & (NB * LQ - 1);
    unsigned long long a  = (unsigned)ha[k];
    unsigned long long bb = (unsigned)hb[k];
    __shared__ int ids[S_SET];
    if (k < S_SET) ids[k] = ts[idx * S_SET + k];
    __syncthreads();
    unsigned mn = 0xFFFFFFFFu;
    #pragma unroll
    for (int s = 0; s < S_SET; s++) {
        unsigned long long x = a * (unsigned long long)(unsigned)ids[s] + bb;
        x = (x & PRIME) + (x >> 31);      // 2^31 == 1 (mod 2^31-1)
        x = (x & PRIME) + (x >> 31);
        unsigned r = (unsigned)x;
        if (r >= PRIME) r -= PRIME;
        mn = (r < mn) ? r : mn;
    }
    sig[idx * K_HASH + k] = (ushort_t)mn;
}

// ---------------------------------------------------------------------------
// 2) Jaccard v3: 128x64 tile, 512 blocks (2 waves/SIMD), 8x4 per thread.
//    ALL 4 hash chunks staged up-front (2 barriers total, ~50KB LDS,
//    2 blocks/CU). Swizzle algebra: both Q and K reads at pass cc resolve
//    to GLOBAL hash group cc (store rotation cancels read rotation);
//    Qs reads conflict-free, Ks reads 2-way (free, m136).
// ---------------------------------------------------------------------------
__global__ __launch_bounds__(256) void jaccard_kernel(
        const ushort_t* __restrict__ sig_q, const ushort_t* __restrict__ sig_k,
        ushort_t* __restrict__ P, float* __restrict__ rs) {
    __shared__ int Qs[4][128 * 16];       // 32 KB
    __shared__ int Ks[4][64 * 17];        // 17.4 KB (17-word pitch)
    __shared__ float lut[K_HASH + 1];
    int tid = threadIdx.x;
    if (tid <= K_HASH) {
        float r = (float)(K_HASH - tid) / (float)(K_HASH + tid); // (1-J)/(1+J)
        lut[tid] = expf(expf(-GAMMA * (2.0f * S_SET) * r));      // softmax numer
    }
    int b = blockIdx.z;
    int q0 = blockIdx.y * 128, j0 = blockIdx.x * 64;
    const int4* gq = (const int4*)(sig_q + ((size_t)b * LQ + q0) * K_HASH);
    const int4* gk = (const int4*)(sig_k + ((size_t)b * LK + j0) * K_HASH);
    int r0 = tid >> 2, g0 = tid & 3;      // r0: 0..63
    int r1 = 64 + r0;
    #pragma unroll
    for (int ch = 0; ch < 4; ch++) {
        *(int4*)&Qs[ch][r0 * 16 + ((g0 + (r0 >> 3)) & 3) * 4] = gq[r0 * 16 + ch * 4 + g0];
        *(int4*)&Qs[ch][r1 * 16 + ((g0 + (r1 >> 3)) & 3) * 4] = gq[r1 * 16 + ch * 4 + g0];
        *(int4*)&Ks[ch][r0 * 17 + ((g0 + (r0 >> 5)) & 3) * 4] = gk[r0 * 16 + ch * 4 + g0];
    }
    __syncthreads();
    int tx = tid & 15, ty = tid >> 4;     // tx: j-group (4 cols), ty: q-group (8 rows)
    unsigned acc[8][4] = {};
    #pragma unroll 1
    for (int ch = 0; ch < 4; ch++) {
        #pragma unroll
        for (int cc = 0; cc < 4; cc++) {
            int4 qv[8], kv[4];
            #pragma unroll
            for (int i = 0; i < 8; i++)
                qv[i] = *(const int4*)&Qs[ch][(ty * 8 + i) * 16 + ((cc + ty) & 3) * 4];
            #pragma unroll
            for (int j = 0; j < 4; j++)
                kv[j] = *(const int4*)&Ks[ch][(tx * 4 + j) * 17 + ((cc + (tx >> 3)) & 3) * 4];
            #pragma unroll
            for (int i = 0; i < 8; i++)
                #pragma unroll
                for (int j = 0; j < 4; j++)
                    acc[i][j] = nm8(acc[i][j], qv[i], kv[j]);
        }
    }
    // counts -> P (bf16) + per-row partial sums
    ushort_t* Pb = P + (size_t)b * LQ * LK;
    float fsum[8];
    #pragma unroll
    for (int i = 0; i < 8; i++) {
        float s = 0.f;
        ushort4 o;
        unsigned nm0 = (acc[i][0] & 0xFFFFu) + (acc[i][0] >> 16);
        unsigned nm1 = (acc[i][1] & 0xFFFFu) + (acc[i][1] >> 16);
        unsigned nm2_ = (acc[i][2] & 0xFFFFu) + (acc[i][2] >> 16);
        unsigned nm3 = (acc[i][3] & 0xFFFFu) + (acc[i][3] >> 16);
        float p0 = lut[K_HASH - nm0], p1 = lut[K_HASH - nm1];
        float p2 = lut[K_HASH - nm2_], p3 = lut[K_HASH - nm3];
        s = (p0 + p1) + (p2 + p3);
        o.x = f2bf(p0); o.y = f2bf(p1); o.z = f2bf(p2); o.w = f2bf(p3);
        fsum[i] = s;
        int row = q0 + ty * 8 + i;
        *(ushort4*)&Pb[(size_t)row * LK + j0 + tx * 4] = o;
    }
    __syncthreads();                      // compute done; reuse Qs as f32 scratch
    float* fs = (float*)&Qs[0][0];        // [128 rows][16 tx]
    #pragma unroll
    for (int i = 0; i < 8; i++) fs[(ty * 8 + i) * 16 + tx] = fsum[i];
    __syncthreads();
    if (tid < 128) {
        float s = 0.f;
        #pragma unroll
        for (int t = 0; t < 16; t++) s += fs[tid * 16 + t];
        atomicAdd(&rs[(size_t)b * LQ + q0 + tid], s);
    }
}

// ---------------------------------------------------------------------------
// 4) bf16 BT-GEMM: C[M,N] = A[M,K] @ B[N,K]^T (+epilogue), f32 accum.
//    64x64 tile, 256 thr (4 waves x 32x32), glds width-16, XOR-swizzled LDS,
//    double-buffered. 512-block grids -> 2 waves/SIMD.
// ---------------------------------------------------------------------------
#define EPI_ROWBIAS  0
#define EPI_ROWDIV   1
#define EPI_COLBIAS  2

template<int OUTF32, int MODE>
__global__ __launch_bounds__(256) void btgemm_kernel(
        const ushort_t* __restrict__ A, const ushort_t* __restrict__ B,
        void* __restrict__ C,
        const float* __restrict__ bias, const float* __restrict__ scale,
        int lda, int ldb, int ldc, int Kd,
        long long sA, long long sB, long long sC, long long sS) {
    __shared__ ushort_t As[2][64 * 32];   // 4 KB x2
    __shared__ ushort_t Bs[2][64 * 32];   // 4 KB x2
    int z = blockIdx.z;
    int m0 = blockIdx.y * 64, n0 = blockIdx.x * 64;
    int tid = threadIdx.x;
    int w = tid >> 6, lane = tid & 63;
    int wm = (w & 1) * 32, wn = (w >> 1) * 32;
    int mrow = lane & 15, kg = lane >> 4;

    int r = tid >> 2, c = (tid & 3) ^ SWZ(r);
    const ushort_t* pa = A + (size_t)z * sA + (size_t)(m0 + r) * lda + c * 8;
    const ushort_t* pb = B + (size_t)z * sB + (size_t)(n0 + r) * ldb + c * 8;

    int aoff[2], boff[2];
    #pragma unroll
    for (int s = 0; s < 2; s++) {
        int Ra = wm + s * 16 + mrow;
        aoff[s] = Ra * 32 + (kg ^ SWZ(Ra)) * 8;
        int Rb = wn + s * 16 + mrow;
        boff[s] = Rb * 32 + (kg ^ SWZ(Rb)) * 8;
    }

    f32x4 acc[2][2] = {};
    int nK = Kd >> 5;
    glds16(pa, &As[0][tid * 8]);
    glds16(pb, &Bs[0][tid * 8]);
    for (int i = 0; i < nK; i++) {
        __syncthreads();
        int cur = i & 1, nxt = cur ^ 1;
        if (i + 1 < nK) {
            int k0 = (i + 1) << 5;
            glds16(pa + k0, &As[nxt][tid * 8]);
            glds16(pb + k0, &Bs[nxt][tid * 8]);
        }
        short8 af[2], bh[2];
        #pragma unroll
        for (int s = 0; s < 2; s++) {
            af[s] = *(const short8*)&As[cur][aoff[s]];
            bh[s] = *(const short8*)&Bs[cur][boff[s]];
        }
        #pragma unroll
        for (int ii = 0; ii < 2; ii++)
            #pragma unroll
            for (int jj = 0; jj < 2; jj++)
                acc[ii][jj] = __builtin_amdgcn_mfma_f32_16x16x32_bf16(
                                  af[ii], bh[jj], acc[ii][jj], 0, 0, 0);
    }

    const float* sc = scale + (size_t)z * sS;
    int col = lane & 15, rbase = (lane >> 4) * 4;
    #pragma unroll
    for (int ii = 0; ii < 2; ii++) {
        #pragma unroll
        for (int jj = 0; jj < 2; jj++) {
            #pragma unroll
            for (int rr = 0; rr < 4; rr++) {
                int gm = m0 + wm + ii * 16 + rbase + rr;
                int gn = n0 + wn + jj * 16 + col;
                float v = acc[ii][jj][rr];
                if (MODE == EPI_ROWBIAS)     v += bias[gm];
                else if (MODE == EPI_ROWDIV) v /= sc[gm];
                else                         v += bias[gn];
                size_t cix = (size_t)z * sC + (size_t)gm * ldc + gn;
                if (OUTF32) ((float*)C)[cix] = v;
                else        ((ushort_t*)C)[cix] = f2bf(v);
            }
        }
    }
}

// ---------------------------------------------------------------------------
extern "C" void kernel_launch(void* const* d_in, const int* in_sizes, int n_in,
                              void* d_out, int out_size, void* d_ws, size_t ws_size,
                              hipStream_t stream) {
    // inputs: 0 query 1 key 2 value 3 ts_q 4 ts_k 5 ha 6 hb 7 Wq 8 bq 9 Wk 10 bk
    //         11 Wv 12 bv 13 Wo 14 bo   (q/k projections are dead code)
    const float* value = (const float*)d_in[2];
    const int* tsq = (const int*)d_in[3];
    const int* tsk = (const int*)d_in[4];
    const int* ha  = (const int*)d_in[5];
    const int* hb  = (const int*)d_in[6];
    const float* Wv = (const float*)d_in[11];
    const float* bv = (const float*)d_in[12];
    const float* Wo = (const float*)d_in[13];
    const float* bo = (const float*)d_in[14];
    float* out = (float*)d_out;

    char* ws = (char*)d_ws;
    ushort_t* sigq   = (ushort_t*)(ws);                              // 1 MB
    ushort_t* sigk   = (ushort_t*)(ws + (1ull << 20));               // 1 MB
    ushort_t* P      = (ushort_t*)(ws + (4ull << 20));               // 8 MB
    float* rs        = (float*)(ws + (12ull << 20));                 // 16 KB
    ushort_t* Vt     = (ushort_t*)(ws + (12ull << 20) + (1ull << 16)); // 4 MB [512 x 4096]
    ushort_t* ctx    = (ushort_t*)(ws + (17ull << 20));              // 4 MB [4096 x 512]
    ushort_t* Vb     = (ushort_t*)(ws + (21ull << 20));              // 4 MB [4096 x 512]
    ushort_t* Wvb    = (ushort_t*)(ws + (25ull << 20));              // 512 KB
    ushort_t* Wob    = (ushort_t*)(ws + (25ull << 20) + (512ull << 10)); // 512 KB

    // 0) f32 -> bf16 for GEMM operands
    cvt_kernel<<<(CVT_N0 + CVT_N1 + CVT_N2) / (256 * 8), 256, 0, stream>>>(
        value, Wv, Wo, Vb, Wvb, Wob);

    // 1) signatures (+ zero rs)
    sig_kernel<<<2 * NB * LQ, 128, 0, stream>>>(tsq, tsk, ha, hb, sigq, sigk, rs);

    // 2) P = exp(score) (bf16) + row sums into rs
    jaccard_kernel<<<dim3(LK / 64, LQ / 128, NB), 256, 0, stream>>>(sigq, sigk, P, rs);

    // 4) Vt[d, b*1024+j] = sum_e Wvb[d,e]*Vb[b*1024+j, e] + bv[d]
    btgemm_kernel<0, EPI_ROWBIAS><<<dim3(4096 / 64, 512 / 64, 1), 256, 0, stream>>>(
        Wvb, Vb, Vt, bv, rs /*unused*/,
        EDIM, EDIM, NB * LK, EDIM, 0LL, 0LL, 0LL, 0LL);

    // 5) ctx[b*1024+q, d] = (1/rs[b,q]) * sum_j P[b,q,j]*Vt[d, b*1024+j]
    btgemm_kernel<0, EPI_ROWDIV><<<dim3(EDIM / 64, LQ / 64, NB), 256, 0, stream>>>(
        P, Vt, ctx, bv /*unused*/, rs,
        LK, NB * LK, EDIM, LK,
        (long long)LQ * LK, (long long)LK, (long long)LQ * EDIM, (long long)LQ);

    // 6) out[bq, n] = sum_e ctx[bq,e]*Wob[n,e] + bo[n]  (f32 -> d_out)
    btgemm_kernel<1, EPI_COLBIAS><<<dim3(EDIM / 64, NB * LQ / 64, 1), 256, 0, stream>>>(
        ctx, Wob, out, bo, rs /*unused*/,
        EDIM, EDIM, EDIM, EDIM, 0LL, 0LL, 0LL, 0LL);
}

// Round 6
// 156.592 us; speedup vs baseline: 1.3039x; 1.1830x over previous
//
#include <hip/hip_runtime.h>
#include <hip/hip_bf16.h>
#include <stdint.h>

// Problem constants (fixed by setup_inputs)
#define PRIME 2147483647u
#define GAMMA 0.3f
#define K_HASH 128
#define S_SET 8
#define NB 4
#define LQ 1024
#define LK 1024
#define EDIM 512

typedef unsigned short ushort_t;
typedef __attribute__((ext_vector_type(8))) short short8;
typedef __attribute__((ext_vector_type(4))) float f32x4;

static __device__ __forceinline__ unsigned short f2bf(float f) {
    unsigned u = __builtin_bit_cast(unsigned, f);
    u += 0x7FFFu + ((u >> 16) & 1u);   // RNE (no NaN in this problem)
    return (unsigned short)(u >> 16);
}

// async global->LDS, 16B per lane; LDS dst must be lane-contiguous.
static __device__ __forceinline__ void glds16(const void* g, void* l) {
    __builtin_amdgcn_global_load_lds(
        (const __attribute__((address_space(1))) unsigned int*)g,
        (__attribute__((address_space(3))) unsigned int*)l, 16, 0, 0);
}

#define SWZ(r) ((((r) >> 2) & 3) ^ ((r) & 3))

// packed nonmatch accumulate: acc += per-half min(a^b, 1).
// Forced v_pk_min_u16 (VOP3P): LLVM scalarizes __builtin_elementwise_min on
// u16x2 into ~8 ops/word (R5 counters: 24k VALU instr/wave vs 6k modeled).
// 'ones' lives in a VGPR so BOTH halves clamp to 1 (inline-const op_sel_hi
// would feed 0 to the hi half).
static __device__ __forceinline__ unsigned nm2(unsigned acc, unsigned a,
                                               unsigned b, unsigned ones) {
    unsigned x = a ^ b, t;
    asm("v_pk_min_u16 %0, %1, %2" : "=v"(t) : "v"(x), "v"(ones));
    return acc + t;                       // halves <= 64: no cross-half carry
}
static __device__ __forceinline__ unsigned nm8(unsigned acc, int4 q, int4 k,
                                               unsigned ones) {
    acc = nm2(acc, (unsigned)q.x, (unsigned)k.x, ones);
    acc = nm2(acc, (unsigned)q.y, (unsigned)k.y, ones);
    acc = nm2(acc, (unsigned)q.z, (unsigned)k.z, ones);
    acc = nm2(acc, (unsigned)q.w, (unsigned)k.w, ones);
    return acc;
}

// ---------------------------------------------------------------------------
// 0) f32 -> bf16 pre-convert for value / Wv / Wo
// ---------------------------------------------------------------------------
#define CVT_N0 (NB * LK * EDIM)
#define CVT_N1 (EDIM * EDIM)
#define CVT_N2 (EDIM * EDIM)
__global__ __launch_bounds__(256) void cvt_kernel(
        const float* __restrict__ v, const float* __restrict__ wv,
        const float* __restrict__ wo,
        ushort_t* __restrict__ vb, ushort_t* __restrict__ wvb,
        ushort_t* __restrict__ wob) {
    size_t i = ((size_t)blockIdx.x * 256 + threadIdx.x) * 8;
    const float* src; ushort_t* dst; size_t off;
    if (i < CVT_N0)                { src = v;  dst = vb;  off = i; }
    else if (i < CVT_N0 + CVT_N1)  { src = wv; dst = wvb; off = i - CVT_N0; }
    else                           { src = wo; dst = wob; off = i - CVT_N0 - CVT_N1; }
    float4 a = *(const float4*)(src + off);
    float4 b = *(const float4*)(src + off + 4);
    ushort4 o0, o1;
    o0.x = f2bf(a.x); o0.y = f2bf(a.y); o0.z = f2bf(a.z); o0.w = f2bf(a.w);
    o1.x = f2bf(b.x); o1.y = f2bf(b.y); o1.z = f2bf(b.z); o1.w = f2bf(b.w);
    *(ushort4*)(dst + off)     = o0;
    *(ushort4*)(dst + off + 4) = o1;
}

// ---------------------------------------------------------------------------
// 1) MinHash signatures -> low-16-bit truncated (equality FP rate 2^-16,
//    output-level effect ~1e-6 << 5e-4 threshold). Also zeroes rowsum buf.
// ---------------------------------------------------------------------------
__global__ __launch_bounds__(128) void sig_kernel(
        const int* __restrict__ ts_q, const int* __restrict__ ts_k,
        const int* __restrict__ ha, const int* __restrict__ hb,
        ushort_t* __restrict__ sig_q, ushort_t* __restrict__ sig_k,
        float* __restrict__ rs) {
    int blk = blockIdx.x;
    int k = threadIdx.x;
    if (blk < 32) rs[blk * 128 + k] = 0.f;   // zero rowsum[4096] (ws is poisoned)
    const int* ts = (blk < NB * LQ) ? ts_q : ts_k;
    ushort_t* sig = (blk < NB * LQ) ? sig_q : sig_k;
    int idx = blk & (NB * LQ - 1);
    unsigned long long a  = (unsigned)ha[k];
    unsigned long long bb = (unsigned)hb[k];
    __shared__ int ids[S_SET];
    if (k < S_SET) ids[k] = ts[idx * S_SET + k];
    __syncthreads();
    unsigned mn = 0xFFFFFFFFu;
    #pragma unroll
    for (int s = 0; s < S_SET; s++) {
        unsigned long long x = a * (unsigned long long)(unsigned)ids[s] + bb;
        x = (x & PRIME) + (x >> 31);      // 2^31 == 1 (mod 2^31-1)
        x = (x & PRIME) + (x >> 31);
        unsigned r = (unsigned)x;
        if (r >= PRIME) r -= PRIME;
        mn = (r < mn) ? r : mn;
    }
    sig[idx * K_HASH + k] = (ushort_t)mn;
}

// ---------------------------------------------------------------------------
// 2) Jaccard v4: 128x64 tile, 512 blocks (2 waves/SIMD), 8x4 per thread.
//    ALL 4 hash chunks staged up-front (2 barriers, ~50KB LDS, 2 blk/CU).
//    Swizzle: both Q and K reads at pass cc resolve to GLOBAL hash group cc;
//    Qs reads conflict-free, Ks reads 2-way (free, m136).
//    v4 = v3 + forced v_pk_min_u16 (see nm2).
// ---------------------------------------------------------------------------
__global__ __launch_bounds__(256) void jaccard_kernel(
        const ushort_t* __restrict__ sig_q, const ushort_t* __restrict__ sig_k,
        ushort_t* __restrict__ P, float* __restrict__ rs) {
    __shared__ int Qs[4][128 * 16];       // 32 KB
    __shared__ int Ks[4][64 * 17];        // 17.4 KB (17-word pitch)
    __shared__ float lut[K_HASH + 1];
    int tid = threadIdx.x;
    if (tid <= K_HASH) {
        float r = (float)(K_HASH - tid) / (float)(K_HASH + tid); // (1-J)/(1+J)
        lut[tid] = expf(expf(-GAMMA * (2.0f * S_SET) * r));      // softmax numer
    }
    int b = blockIdx.z;
    int q0 = blockIdx.y * 128, j0 = blockIdx.x * 64;
    const int4* gq = (const int4*)(sig_q + ((size_t)b * LQ + q0) * K_HASH);
    const int4* gk = (const int4*)(sig_k + ((size_t)b * LK + j0) * K_HASH);
    int r0 = tid >> 2, g0 = tid & 3;      // r0: 0..63
    int r1 = 64 + r0;
    #pragma unroll
    for (int ch = 0; ch < 4; ch++) {
        *(int4*)&Qs[ch][r0 * 16 + ((g0 + (r0 >> 3)) & 3) * 4] = gq[r0 * 16 + ch * 4 + g0];
        *(int4*)&Qs[ch][r1 * 16 + ((g0 + (r1 >> 3)) & 3) * 4] = gq[r1 * 16 + ch * 4 + g0];
        *(int4*)&Ks[ch][r0 * 17 + ((g0 + (r0 >> 5)) & 3) * 4] = gk[r0 * 16 + ch * 4 + g0];
    }
    __syncthreads();
    int tx = tid & 15, ty = tid >> 4;     // tx: j-group (4 cols), ty: q-group (8 rows)
    unsigned ones = 0x00010001u;
    unsigned acc[8][4] = {};
    #pragma unroll 1
    for (int ch = 0; ch < 4; ch++) {
        #pragma unroll
        for (int cc = 0; cc < 4; cc++) {
            int4 qv[8], kv[4];
            #pragma unroll
            for (int i = 0; i < 8; i++)
                qv[i] = *(const int4*)&Qs[ch][(ty * 8 + i) * 16 + ((cc + ty) & 3) * 4];
            #pragma unroll
            for (int j = 0; j < 4; j++)
                kv[j] = *(const int4*)&Ks[ch][(tx * 4 + j) * 17 + ((cc + (tx >> 3)) & 3) * 4];
            #pragma unroll
            for (int i = 0; i < 8; i++)
                #pragma unroll
                for (int j = 0; j < 4; j++)
                    acc[i][j] = nm8(acc[i][j], qv[i], kv[j], ones);
        }
    }
    // counts -> P (bf16) + per-row partial sums
    ushort_t* Pb = P + (size_t)b * LQ * LK;
    float fsum[8];
    #pragma unroll
    for (int i = 0; i < 8; i++) {
        ushort4 o;
        unsigned nm0 = (acc[i][0] & 0xFFFFu) + (acc[i][0] >> 16);
        unsigned nm1 = (acc[i][1] & 0xFFFFu) + (acc[i][1] >> 16);
        unsigned nm2_ = (acc[i][2] & 0xFFFFu) + (acc[i][2] >> 16);
        unsigned nm3 = (acc[i][3] & 0xFFFFu) + (acc[i][3] >> 16);
        float p0 = lut[K_HASH - nm0], p1 = lut[K_HASH - nm1];
        float p2 = lut[K_HASH - nm2_], p3 = lut[K_HASH - nm3];
        fsum[i] = (p0 + p1) + (p2 + p3);
        o.x = f2bf(p0); o.y = f2bf(p1); o.z = f2bf(p2); o.w = f2bf(p3);
        int row = q0 + ty * 8 + i;
        *(ushort4*)&Pb[(size_t)row * LK + j0 + tx * 4] = o;
    }
    __syncthreads();                      // compute done; reuse Qs as f32 scratch
    float* fs = (float*)&Qs[0][0];        // [128 rows][16 tx]
    #pragma unroll
    for (int i = 0; i < 8; i++) fs[(ty * 8 + i) * 16 + tx] = fsum[i];
    __syncthreads();
    if (tid < 128) {
        float s = 0.f;
        #pragma unroll
        for (int t = 0; t < 16; t++) s += fs[tid * 16 + t];
        atomicAdd(&rs[(size_t)b * LQ + q0 + tid], s);
    }
}

// ---------------------------------------------------------------------------
// 4) bf16 BT-GEMM: C[M,N] = A[M,K] @ B[N,K]^T (+epilogue), f32 accum.
//    64x64 tile, 256 thr (4 waves x 32x32), glds width-16, XOR-swizzled LDS,
//    double-buffered. 512+-block grids -> >=2 waves/SIMD.
// ---------------------------------------------------------------------------
#define EPI_ROWBIAS  0
#define EPI_ROWDIV   1
#define EPI_COLBIAS  2

template<int OUTF32, int MODE>
__global__ __launch_bounds__(256) void btgemm_kernel(
        const ushort_t* __restrict__ A, const ushort_t* __restrict__ B,
        void* __restrict__ C,
        const float* __restrict__ bias, const float* __restrict__ scale,
        int lda, int ldb, int ldc, int Kd,
        long long sA, long long sB, long long sC, long long sS) {
    __shared__ ushort_t As[2][64 * 32];   // 4 KB x2
    __shared__ ushort_t Bs[2][64 * 32];   // 4 KB x2
    int z = blockIdx.z;
    int m0 = blockIdx.y * 64, n0 = blockIdx.x * 64;
    int tid = threadIdx.x;
    int w = tid >> 6, lane = tid & 63;
    int wm = (w & 1) * 32, wn = (w >> 1) * 32;
    int mrow = lane & 15, kg = lane >> 4;

    int r = tid >> 2, c = (tid & 3) ^ SWZ(r);
    const ushort_t* pa = A + (size_t)z * sA + (size_t)(m0 + r) * lda + c * 8;
    const ushort_t* pb = B + (size_t)z * sB + (size_t)(n0 + r) * ldb + c * 8;

    int aoff[2], boff[2];
    #pragma unroll
    for (int s = 0; s < 2; s++) {
        int Ra = wm + s * 16 + mrow;
        aoff[s] = Ra * 32 + (kg ^ SWZ(Ra)) * 8;
        int Rb = wn + s * 16 + mrow;
        boff[s] = Rb * 32 + (kg ^ SWZ(Rb)) * 8;
    }

    f32x4 acc[2][2] = {};
    int nK = Kd >> 5;
    glds16(pa, &As[0][tid * 8]);
    glds16(pb, &Bs[0][tid * 8]);
    for (int i = 0; i < nK; i++) {
        __syncthreads();
        int cur = i & 1, nxt = cur ^ 1;
        if (i + 1 < nK) {
            int k0 = (i + 1) << 5;
            glds16(pa + k0, &As[nxt][tid * 8]);
            glds16(pb + k0, &Bs[nxt][tid * 8]);
        }
        short8 af[2], bh[2];
        #pragma unroll
        for (int s = 0; s < 2; s++) {
            af[s] = *(const short8*)&As[cur][aoff[s]];
            bh[s] = *(const short8*)&Bs[cur][boff[s]];
        }
        #pragma unroll
        for (int ii = 0; ii < 2; ii++)
            #pragma unroll
            for (int jj = 0; jj < 2; jj++)
                acc[ii][jj] = __builtin_amdgcn_mfma_f32_16x16x32_bf16(
                                  af[ii], bh[jj], acc[ii][jj], 0, 0, 0);
    }

    const float* sc = scale + (size_t)z * sS;
    int col = lane & 15, rbase = (lane >> 4) * 4;
    #pragma unroll
    for (int ii = 0; ii < 2; ii++) {
        #pragma unroll
        for (int jj = 0; jj < 2; jj++) {
            #pragma unroll
            for (int rr = 0; rr < 4; rr++) {
                int gm = m0 + wm + ii * 16 + rbase + rr;
                int gn = n0 + wn + jj * 16 + col;
                float v = acc[ii][jj][rr];
                if (MODE == EPI_ROWBIAS)     v += bias[gm];
                else if (MODE == EPI_ROWDIV) v /= sc[gm];
                else                         v += bias[gn];
                size_t cix = (size_t)z * sC + (size_t)gm * ldc + gn;
                if (OUTF32) ((float*)C)[cix] = v;
                else        ((ushort_t*)C)[cix] = f2bf(v);
            }
        }
    }
}

// ---------------------------------------------------------------------------
extern "C" void kernel_launch(void* const* d_in, const int* in_sizes, int n_in,
                              void* d_out, int out_size, void* d_ws, size_t ws_size,
                              hipStream_t stream) {
    // inputs: 0 query 1 key 2 value 3 ts_q 4 ts_k 5 ha 6 hb 7 Wq 8 bq 9 Wk 10 bk
    //         11 Wv 12 bv 13 Wo 14 bo   (q/k projections are dead code)
    const float* value = (const float*)d_in[2];
    const int* tsq = (const int*)d_in[3];
    const int* tsk = (const int*)d_in[4];
    const int* ha  = (const int*)d_in[5];
    const int* hb  = (const int*)d_in[6];
    const float* Wv = (const float*)d_in[11];
    const float* bv = (const float*)d_in[12];
    const float* Wo = (const float*)d_in[13];
    const float* bo = (const float*)d_in[14];
    float* out = (float*)d_out;

    char* ws = (char*)d_ws;
    ushort_t* sigq   = (ushort_t*)(ws);                              // 1 MB
    ushort_t* sigk   = (ushort_t*)(ws + (1ull << 20));               // 1 MB
    ushort_t* P      = (ushort_t*)(ws + (4ull << 20));               // 8 MB
    float* rs        = (float*)(ws + (12ull << 20));                 // 16 KB
    ushort_t* Vt     = (ushort_t*)(ws + (12ull << 20) + (1ull << 16)); // 4 MB [512 x 4096]
    ushort_t* ctx    = (ushort_t*)(ws + (17ull << 20));              // 4 MB [4096 x 512]
    ushort_t* Vb     = (ushort_t*)(ws + (21ull << 20));              // 4 MB [4096 x 512]
    ushort_t* Wvb    = (ushort_t*)(ws + (25ull << 20));              // 512 KB
    ushort_t* Wob    = (ushort_t*)(ws + (25ull << 20) + (512ull << 10)); // 512 KB

    // 0) f32 -> bf16 for GEMM operands
    cvt_kernel<<<(CVT_N0 + CVT_N1 + CVT_N2) / (256 * 8), 256, 0, stream>>>(
        value, Wv, Wo, Vb, Wvb, Wob);

    // 1) signatures (+ zero rs)
    sig_kernel<<<2 * NB * LQ, 128, 0, stream>>>(tsq, tsk, ha, hb, sigq, sigk, rs);

    // 2) P = exp(score) (bf16) + row sums into rs
    jaccard_kernel<<<dim3(LK / 64, LQ / 128, NB), 256, 0, stream>>>(sigq, sigk, P, rs);

    // 4) Vt[d, b*1024+j] = sum_e Wvb[d,e]*Vb[b*1024+j, e] + bv[d]
    btgemm_kernel<0, EPI_ROWBIAS><<<dim3(4096 / 64, 512 / 64, 1), 256, 0, stream>>>(
        Wvb, Vb, Vt, bv, rs /*unused*/,
        EDIM, EDIM, NB * LK, EDIM, 0LL, 0LL, 0LL, 0LL);

    // 5) ctx[b*1024+q, d] = (1/rs[b,q]) * sum_j P[b,q,j]*Vt[d, b*1024+j]
    btgemm_kernel<0, EPI_ROWDIV><<<dim3(EDIM / 64, LQ / 64, NB), 256, 0, stream>>>(
        P, Vt, ctx, bv /*unused*/, rs,
        LK, NB * LK, EDIM, LK,
        (long long)LQ * LK, (long long)LK, (long long)LQ * EDIM, (long long)LQ);

    // 6) out[bq, n] = sum_e ctx[bq,e]*Wob[n,e] + bo[n]  (f32 -> d_out)
    btgemm_kernel<1, EPI_COLBIAS><<<dim3(EDIM / 64, NB * LQ / 64, 1), 256, 0, stream>>>(
        ctx, Wob, out, bo, rs /*unused*/,
        EDIM, EDIM, EDIM, EDIM, 0LL, 0LL, 0LL, 0LL);
}

// Round 7
// 156.572 us; speedup vs baseline: 1.3041x; 1.0001x over previous
//
#include <hip/hip_runtime.h>
#include <hip/hip_bf16.h>
#include <stdint.h>

// Problem constants (fixed by setup_inputs)
#define PRIME 2147483647u
#define GAMMA 0.3f
#define K_HASH 128
#define S_SET 8
#define NB 4
#define LQ 1024
#define LK 1024
#define EDIM 512

typedef unsigned short ushort_t;
typedef __attribute__((ext_vector_type(8))) short short8;
typedef __attribute__((ext_vector_type(4))) float f32x4;

static __device__ __forceinline__ unsigned short f2bf(float f) {
    unsigned u = __builtin_bit_cast(unsigned, f);
    u += 0x7FFFu + ((u >> 16) & 1u);   // RNE (no NaN in this problem)
    return (unsigned short)(u >> 16);
}

// async global->LDS, 16B per lane; LDS dst must be lane-contiguous.
static __device__ __forceinline__ void glds16(const void* g, void* l) {
    __builtin_amdgcn_global_load_lds(
        (const __attribute__((address_space(1))) unsigned int*)g,
        (__attribute__((address_space(3))) unsigned int*)l, 16, 0, 0);
}

#define SWZ(r) ((((r) >> 2) & 3) ^ ((r) & 3))

// packed nonmatch accumulate: acc += per-half min(a^b, 1).
// Forced v_pk_min_u16: LLVM scalarizes __builtin_elementwise_min on u16x2
// (~8 ops/word); this asm keeps it at 3 ops/word (R5->R6: jaccard 55->26 us).
// 'ones' in a VGPR so BOTH halves clamp to 1.
static __device__ __forceinline__ unsigned nm2(unsigned acc, unsigned a,
                                               unsigned b, unsigned ones) {
    unsigned x = a ^ b, t;
    asm("v_pk_min_u16 %0, %1, %2" : "=v"(t) : "v"(x), "v"(ones));
    return acc + t;                       // halves <= 64: no cross-half carry
}
static __device__ __forceinline__ unsigned nm8(unsigned acc, int4 q, int4 k,
                                               unsigned ones) {
    acc = nm2(acc, (unsigned)q.x, (unsigned)k.x, ones);
    acc = nm2(acc, (unsigned)q.y, (unsigned)k.y, ones);
    acc = nm2(acc, (unsigned)q.z, (unsigned)k.z, ones);
    acc = nm2(acc, (unsigned)q.w, (unsigned)k.w, ones);
    return acc;
}

// ---------------------------------------------------------------------------
// 1) prep: fused f32->bf16 convert (value/Wv/Wo) + MinHash signatures.
//    Signatures truncated to low 16 bits (FP rate 2^-16, output effect ~1e-6).
// ---------------------------------------------------------------------------
#define CVT_N0 (NB * LK * EDIM)
#define CVT_N1 (EDIM * EDIM)
#define CVT_N2 (EDIM * EDIM)
#define CVT_BLOCKS ((CVT_N0 + CVT_N1 + CVT_N2) / (256 * 8))   // 1280
#define SIG_BLOCKS (NB * (LQ + LK) / 2)                        // 4096 (2 rows/blk)

__global__ __launch_bounds__(256) void prep_kernel(
        const float* __restrict__ v, const float* __restrict__ wv,
        const float* __restrict__ wo,
        ushort_t* __restrict__ vb, ushort_t* __restrict__ wvb,
        ushort_t* __restrict__ wob,
        const int* __restrict__ ts_q, const int* __restrict__ ts_k,
        const int* __restrict__ ha, const int* __restrict__ hb,
        ushort_t* __restrict__ sig_q, ushort_t* __restrict__ sig_k,
        float* __restrict__ rs) {
    int blk = blockIdx.x;
    if (blk < CVT_BLOCKS) {               // ---- convert branch ----
        size_t i = ((size_t)blk * 256 + threadIdx.x) * 8;
        const float* src; ushort_t* dst; size_t off;
        if (i < CVT_N0)                { src = v;  dst = vb;  off = i; }
        else if (i < CVT_N0 + CVT_N1)  { src = wv; dst = wvb; off = i - CVT_N0; }
        else                           { src = wo; dst = wob; off = i - CVT_N0 - CVT_N1; }
        float4 a = *(const float4*)(src + off);
        float4 b = *(const float4*)(src + off + 4);
        ushort4 o0, o1;
        o0.x = f2bf(a.x); o0.y = f2bf(a.y); o0.z = f2bf(a.z); o0.w = f2bf(a.w);
        o1.x = f2bf(b.x); o1.y = f2bf(b.y); o1.z = f2bf(b.z); o1.w = f2bf(b.w);
        *(ushort4*)(dst + off)     = o0;
        *(ushort4*)(dst + off + 4) = o1;
        return;
    }
    // ---- signature branch: 2 token-sets per block (128 threads each) ----
    int sb = blk - CVT_BLOCKS;            // 0..4095
    if (sb < 16) rs[sb * 256 + threadIdx.x] = 0.f;  // zero rowsum[4096]
    int half = threadIdx.x >> 7, k = threadIdx.x & 127;
    int row = sb * 2 + half;              // 0..8191 (halves never straddle 4096)
    const int* ts = (row < NB * LQ) ? ts_q : ts_k;
    ushort_t* sig = (row < NB * LQ) ? sig_q : sig_k;
    int idx = row & (NB * LQ - 1);
    unsigned long long a  = (unsigned)ha[k];
    unsigned long long bb = (unsigned)hb[k];
    __shared__ int ids[2][S_SET];
    if (k < S_SET) ids[half][k] = ts[idx * S_SET + k];
    __syncthreads();
    unsigned mn = 0xFFFFFFFFu;
    #pragma unroll
    for (int s = 0; s < S_SET; s++) {
        unsigned long long x = a * (unsigned long long)(unsigned)ids[half][s] + bb;
        x = (x & PRIME) + (x >> 31);      // 2^31 == 1 (mod 2^31-1)
        x = (x & PRIME) + (x >> 31);
        unsigned r = (unsigned)x;
        if (r >= PRIME) r -= PRIME;
        mn = (r < mn) ? r : mn;
    }
    sig[idx * K_HASH + k] = (ushort_t)mn;
}

// ---------------------------------------------------------------------------
// 2) Jaccard v5: 128x64 tile, 512 blocks, 8x4/thread, all chunks staged
//    up-front (~50KB LDS). v5 = v4 + register double-buffer software
//    pipeline: pass p+1's 12 ds_read_b128 issued BEFORE pass p's 384-op
//    VALU block consumes its data (R6: 40% issue efficiency from exposed
//    LDS latency at 2 waves/SIMD).
// ---------------------------------------------------------------------------
__global__ __launch_bounds__(256) void jaccard_kernel(
        const ushort_t* __restrict__ sig_q, const ushort_t* __restrict__ sig_k,
        ushort_t* __restrict__ P, float* __restrict__ rs) {
    __shared__ int Qs[4][128 * 16];       // 32 KB
    __shared__ int Ks[4][64 * 17];        // 17.4 KB (17-word pitch)
    __shared__ float lut[K_HASH + 1];
    int tid = threadIdx.x;
    if (tid <= K_HASH) {
        float r = (float)(K_HASH - tid) / (float)(K_HASH + tid); // (1-J)/(1+J)
        lut[tid] = expf(expf(-GAMMA * (2.0f * S_SET) * r));      // softmax numer
    }
    int b = blockIdx.z;
    int q0 = blockIdx.y * 128, j0 = blockIdx.x * 64;
    const int4* gq = (const int4*)(sig_q + ((size_t)b * LQ + q0) * K_HASH);
    const int4* gk = (const int4*)(sig_k + ((size_t)b * LK + j0) * K_HASH);
    int r0 = tid >> 2, g0 = tid & 3;      // r0: 0..63
    int r1 = 64 + r0;
    #pragma unroll
    for (int ch = 0; ch < 4; ch++) {
        *(int4*)&Qs[ch][r0 * 16 + ((g0 + (r0 >> 3)) & 3) * 4] = gq[r0 * 16 + ch * 4 + g0];
        *(int4*)&Qs[ch][r1 * 16 + ((g0 + (r1 >> 3)) & 3) * 4] = gq[r1 * 16 + ch * 4 + g0];
        *(int4*)&Ks[ch][r0 * 17 + ((g0 + (r0 >> 5)) & 3) * 4] = gk[r0 * 16 + ch * 4 + g0];
    }
    __syncthreads();
    int tx = tid & 15, ty = tid >> 4;     // tx: j-group (4 cols), ty: q-group (8 rows)
    unsigned ones = 0x00010001u;
    unsigned acc[8][4] = {};

    auto ldq = [&](int ch, int cc, int4* qd) {
        #pragma unroll
        for (int i = 0; i < 8; i++)
            qd[i] = *(const int4*)&Qs[ch][(ty * 8 + i) * 16 + ((cc + ty) & 3) * 4];
    };
    auto ldk = [&](int ch, int cc, int4* kd) {
        #pragma unroll
        for (int j = 0; j < 4; j++)
            kd[j] = *(const int4*)&Ks[ch][(tx * 4 + j) * 17 + ((cc + (tx >> 3)) & 3) * 4];
    };

    int4 qa[8], ka[4], qb[8], kb[4];
    ldq(0, 0, qa); ldk(0, 0, ka);
    #pragma unroll 1
    for (int ch = 0; ch < 4; ch++) {
        #pragma unroll
        for (int cc = 0; cc < 4; cc++) {
            int nch = (cc == 3) ? ((ch + 1) & 3) : ch;   // wraps to (0,0) at end: dead read
            int ncc = (cc + 1) & 3;
            ldq(nch, ncc, qb); ldk(nch, ncc, kb);        // prefetch next pass
            #pragma unroll
            for (int i = 0; i < 8; i++)
                #pragma unroll
                for (int j = 0; j < 4; j++)
                    acc[i][j] = nm8(acc[i][j], qa[i], ka[j], ones);
            #pragma unroll
            for (int i = 0; i < 8; i++) qa[i] = qb[i];
            #pragma unroll
            for (int j = 0; j < 4; j++) ka[j] = kb[j];
        }
    }
    // counts -> P (bf16) + per-row partial sums
    ushort_t* Pb = P + (size_t)b * LQ * LK;
    float fsum[8];
    #pragma unroll
    for (int i = 0; i < 8; i++) {
        ushort4 o;
        unsigned nm0 = (acc[i][0] & 0xFFFFu) + (acc[i][0] >> 16);
        unsigned nm1 = (acc[i][1] & 0xFFFFu) + (acc[i][1] >> 16);
        unsigned nm2_ = (acc[i][2] & 0xFFFFu) + (acc[i][2] >> 16);
        unsigned nm3 = (acc[i][3] & 0xFFFFu) + (acc[i][3] >> 16);
        float p0 = lut[K_HASH - nm0], p1 = lut[K_HASH - nm1];
        float p2 = lut[K_HASH - nm2_], p3 = lut[K_HASH - nm3];
        fsum[i] = (p0 + p1) + (p2 + p3);
        o.x = f2bf(p0); o.y = f2bf(p1); o.z = f2bf(p2); o.w = f2bf(p3);
        int row = q0 + ty * 8 + i;
        *(ushort4*)&Pb[(size_t)row * LK + j0 + tx * 4] = o;
    }
    __syncthreads();                      // compute done; reuse Qs as f32 scratch
    float* fs = (float*)&Qs[0][0];        // [128 rows][16 tx]
    #pragma unroll
    for (int i = 0; i < 8; i++) fs[(ty * 8 + i) * 16 + tx] = fsum[i];
    __syncthreads();
    if (tid < 128) {
        float s = 0.f;
        #pragma unroll
        for (int t = 0; t < 16; t++) s += fs[tid * 16 + t];
        atomicAdd(&rs[(size_t)b * LQ + q0 + tid], s);
    }
}

// ---------------------------------------------------------------------------
// 4) bf16 BT-GEMM: C[M,N] = A[M,K] @ B[N,K]^T (+epilogue), f32 accum.
//    64x64 tile, 256 thr (4 waves x 32x32), glds width-16, XOR-swizzled LDS,
//    double-buffered. 512+-block grids -> >=2 waves/SIMD.
// ---------------------------------------------------------------------------
#define EPI_ROWBIAS  0
#define EPI_ROWDIV   1
#define EPI_COLBIAS  2

template<int OUTF32, int MODE>
__global__ __launch_bounds__(256) void btgemm_kernel(
        const ushort_t* __restrict__ A, const ushort_t* __restrict__ B,
        void* __restrict__ C,
        const float* __restrict__ bias, const float* __restrict__ scale,
        int lda, int ldb, int ldc, int Kd,
        long long sA, long long sB, long long sC, long long sS) {
    __shared__ ushort_t As[2][64 * 32];   // 4 KB x2
    __shared__ ushort_t Bs[2][64 * 32];   // 4 KB x2
    int z = blockIdx.z;
    int m0 = blockIdx.y * 64, n0 = blockIdx.x * 64;
    int tid = threadIdx.x;
    int w = tid >> 6, lane = tid & 63;
    int wm = (w & 1) * 32, wn = (w >> 1) * 32;
    int mrow = lane & 15, kg = lane >> 4;

    int r = tid >> 2, c = (tid & 3) ^ SWZ(r);
    const ushort_t* pa = A + (size_t)z * sA + (size_t)(m0 + r) * lda + c * 8;
    const ushort_t* pb = B + (size_t)z * sB + (size_t)(n0 + r) * ldb + c * 8;

    int aoff[2], boff[2];
    #pragma unroll
    for (int s = 0; s < 2; s++) {
        int Ra = wm + s * 16 + mrow;
        aoff[s] = Ra * 32 + (kg ^ SWZ(Ra)) * 8;
        int Rb = wn + s * 16 + mrow;
        boff[s] = Rb * 32 + (kg ^ SWZ(Rb)) * 8;
    }

    f32x4 acc[2][2] = {};
    int nK = Kd >> 5;
    glds16(pa, &As[0][tid * 8]);
    glds16(pb, &Bs[0][tid * 8]);
    for (int i = 0; i < nK; i++) {
        __syncthreads();
        int cur = i & 1, nxt = cur ^ 1;
        if (i + 1 < nK) {
            int k0 = (i + 1) << 5;
            glds16(pa + k0, &As[nxt][tid * 8]);
            glds16(pb + k0, &Bs[nxt][tid * 8]);
        }
        short8 af[2], bh[2];
        #pragma unroll
        for (int s = 0; s < 2; s++) {
            af[s] = *(const short8*)&As[cur][aoff[s]];
            bh[s] = *(const short8*)&Bs[cur][boff[s]];
        }
        #pragma unroll
        for (int ii = 0; ii < 2; ii++)
            #pragma unroll
            for (int jj = 0; jj < 2; jj++)
                acc[ii][jj] = __builtin_amdgcn_mfma_f32_16x16x32_bf16(
                                  af[ii], bh[jj], acc[ii][jj], 0, 0, 0);
    }

    const float* sc = scale + (size_t)z * sS;
    int col = lane & 15, rbase = (lane >> 4) * 4;
    #pragma unroll
    for (int ii = 0; ii < 2; ii++) {
        #pragma unroll
        for (int jj = 0; jj < 2; jj++) {
            #pragma unroll
            for (int rr = 0; rr < 4; rr++) {
                int gm = m0 + wm + ii * 16 + rbase + rr;
                int gn = n0 + wn + jj * 16 + col;
                float v = acc[ii][jj][rr];
                if (MODE == EPI_ROWBIAS)     v += bias[gm];
                else if (MODE == EPI_ROWDIV) v /= sc[gm];
                else                         v += bias[gn];
                size_t cix = (size_t)z * sC + (size_t)gm * ldc + gn;
                if (OUTF32) ((float*)C)[cix] = v;
                else        ((ushort_t*)C)[cix] = f2bf(v);
            }
        }
    }
}

// ---------------------------------------------------------------------------
extern "C" void kernel_launch(void* const* d_in, const int* in_sizes, int n_in,
                              void* d_out, int out_size, void* d_ws, size_t ws_size,
                              hipStream_t stream) {
    // inputs: 0 query 1 key 2 value 3 ts_q 4 ts_k 5 ha 6 hb 7 Wq 8 bq 9 Wk 10 bk
    //         11 Wv 12 bv 13 Wo 14 bo   (q/k projections are dead code)
    const float* value = (const float*)d_in[2];
    const int* tsq = (const int*)d_in[3];
    const int* tsk = (const int*)d_in[4];
    const int* ha  = (const int*)d_in[5];
    const int* hb  = (const int*)d_in[6];
    const float* Wv = (const float*)d_in[11];
    const float* bv = (const float*)d_in[12];
    const float* Wo = (const float*)d_in[13];
    const float* bo = (const float*)d_in[14];
    float* out = (float*)d_out;

    char* ws = (char*)d_ws;
    ushort_t* sigq   = (ushort_t*)(ws);                              // 1 MB
    ushort_t* sigk   = (ushort_t*)(ws + (1ull << 20));               // 1 MB
    ushort_t* P      = (ushort_t*)(ws + (4ull << 20));               // 8 MB
    float* rs        = (float*)(ws + (12ull << 20));                 // 16 KB
    ushort_t* Vt     = (ushort_t*)(ws + (12ull << 20) + (1ull << 16)); // 4 MB [512 x 4096]
    ushort_t* ctx    = (ushort_t*)(ws + (17ull << 20));              // 4 MB [4096 x 512]
    ushort_t* Vb     = (ushort_t*)(ws + (21ull << 20));              // 4 MB [4096 x 512]
    ushort_t* Wvb    = (ushort_t*)(ws + (25ull << 20));              // 512 KB
    ushort_t* Wob    = (ushort_t*)(ws + (25ull << 20) + (512ull << 10)); // 512 KB

    // 1) fused convert + signatures (+ zero rs)
    prep_kernel<<<CVT_BLOCKS + SIG_BLOCKS, 256, 0, stream>>>(
        value, Wv, Wo, Vb, Wvb, Wob, tsq, tsk, ha, hb, sigq, sigk, rs);

    // 2) P = exp(score) (bf16) + row sums into rs
    jaccard_kernel<<<dim3(LK / 64, LQ / 128, NB), 256, 0, stream>>>(sigq, sigk, P, rs);

    // 4) Vt[d, b*1024+j] = sum_e Wvb[d,e]*Vb[b*1024+j, e] + bv[d]
    btgemm_kernel<0, EPI_ROWBIAS><<<dim3(4096 / 64, 512 / 64, 1), 256, 0, stream>>>(
        Wvb, Vb, Vt, bv, rs /*unused*/,
        EDIM, EDIM, NB * LK, EDIM, 0LL, 0LL, 0LL, 0LL);

    // 5) ctx[b*1024+q, d] = (1/rs[b,q]) * sum_j P[b,q,j]*Vt[d, b*1024+j]
    btgemm_kernel<0, EPI_ROWDIV><<<dim3(EDIM / 64, LQ / 64, NB), 256, 0, stream>>>(
        P, Vt, ctx, bv /*unused*/, rs,
        LK, NB * LK, EDIM, LK,
        (long long)LQ * LK, (long long)LK, (long long)LQ * EDIM, (long long)LQ);

    // 6) out[bq, n] = sum_e ctx[bq,e]*Wob[n,e] + bo[n]  (f32 -> d_out)
    btgemm_kernel<1, EPI_COLBIAS><<<dim3(EDIM / 64, NB * LQ / 64, 1), 256, 0, stream>>>(
        ctx, Wob, out, bo, rs /*unused*/,
        EDIM, EDIM, EDIM, EDIM, 0LL, 0LL, 0LL, 0LL);
}